// Round 1
// baseline (226.090 us; speedup 1.0000x reference)
//
#include <hip/hip_runtime.h>
#include <cstddef>

// Problem constants
#define Bb   32
#define Ss   512
#define Dd   768
#define Ww   256
#define Pp   1024
#define NH   300          // hidden
#define NOUT 600          // 2*NH (top half for slot0, bottom half for slot1)
#define Mm   (Bb * Ww)    // 8192 words total

// -------------------------------------------------------------------------
// Kernel 1: fused mean-pool + GEMM
//   emb[m][k]  = mean of h[b, s0 .. s0+len-1, k]   (len in {1,2}), m = b*W+w
//   proj[m][n] = sum_k emb[m][k] * Bmat[k][n]
//     Bmat[k][n] = (n < 300) ? w1[k][n] : w1[768+k][n-300]
// Tile: BM=64, BN=128, BK=16. 256 threads, each 4x8 outputs.
// -------------------------------------------------------------------------
__global__ __launch_bounds__(256) void bert_pool_gemm_kernel(
    const float* __restrict__ h, const float* __restrict__ w1,
    const int* __restrict__ word_start, const int* __restrict__ word_len,
    float* __restrict__ proj)
{
    __shared__ float As[16][68];   // [kk][row], pad 68 keeps float4 16B-aligned
    __shared__ float Bs[16][128];  // [kk][col]
    __shared__ unsigned long long sOff[64];
    __shared__ float sScale[64];
    __shared__ int   sLen2[64];

    const int t     = threadIdx.x;
    const int mBase = blockIdx.y * 64;
    const int nBase = blockIdx.x * 128;

    if (t < 64) {
        int row = mBase + t;          // flat word index = b*W + w
        int s0  = word_start[row];
        int len = word_len[row];
        int b   = row >> 8;           // / Ww
        sOff[t]   = (unsigned long long)b * (Ss * Dd) + (unsigned long long)s0 * Dd;
        sScale[t] = 1.0f / (float)len;
        sLen2[t]  = (len == 2) ? 1 : 0;
    }
    __syncthreads();

    // A-load role: thread t loads row ar, k-quad ak
    const int ar = t >> 2;
    const int ak = (t & 3) << 2;
    const unsigned long long aOff   = sOff[ar];
    const float              aScale = sScale[ar];
    const int                aLen2  = sLen2[ar];

    // B-load role: thread t loads k-row bk, col octet bn
    const int bk = t >> 4;
    const int bn = (t & 15) << 3;

    // compute role
    const int ty = t >> 4;   // 0..15 -> rows ty*4 .. ty*4+3
    const int tx = t & 15;   // 0..15 -> cols tx*8 .. tx*8+7

    float acc[4][8];
#pragma unroll
    for (int i = 0; i < 4; ++i)
#pragma unroll
        for (int j = 0; j < 8; ++j) acc[i][j] = 0.0f;

    for (int k0 = 0; k0 < Dd; k0 += 16) {
        __syncthreads();   // previous iteration done reading LDS

        // ---- stage A tile (pool on the fly) ----
        {
            const float* p = h + aOff + (size_t)(k0 + ak);
            float4 v = *(const float4*)p;
            if (aLen2) {
                float4 v2 = *(const float4*)(p + Dd);
                v.x += v2.x; v.y += v2.y; v.z += v2.z; v.w += v2.w;
            }
            As[ak + 0][ar] = v.x * aScale;
            As[ak + 1][ar] = v.y * aScale;
            As[ak + 2][ar] = v.z * aScale;
            As[ak + 3][ar] = v.w * aScale;
        }
        // ---- stage B tile ----
        {
            const int k = k0 + bk;
            const float* w1top = w1 + (size_t)k * NH;
            const float* w1bot = w1 + (size_t)(Dd + k) * NH;
#pragma unroll
            for (int j = 0; j < 8; ++j) {
                int n = nBase + bn + j;
                float v;
                if (n < NH)        v = w1top[n];
                else if (n < NOUT) v = w1bot[n - NH];
                else               v = 0.0f;
                Bs[bk][bn + j] = v;
            }
        }
        __syncthreads();

        // ---- 4x8 FMA inner loop ----
#pragma unroll
        for (int kk = 0; kk < 16; ++kk) {
            float4 a4  = *(const float4*)&As[kk][ty * 4];
            float4 bv0 = *(const float4*)&Bs[kk][tx * 8];
            float4 bv1 = *(const float4*)&Bs[kk][tx * 8 + 4];
            float a[4]  = {a4.x, a4.y, a4.z, a4.w};
            float bv[8] = {bv0.x, bv0.y, bv0.z, bv0.w, bv1.x, bv1.y, bv1.z, bv1.w};
#pragma unroll
            for (int i = 0; i < 4; ++i)
#pragma unroll
                for (int j = 0; j < 8; ++j)
                    acc[i][j] = fmaf(a[i], bv[j], acc[i][j]);
        }
    }

    // ---- store (NOUT=600 is 4-divisible; mask whole float4s) ----
#pragma unroll
    for (int i = 0; i < 4; ++i) {
        const int m = mBase + ty * 4 + i;
#pragma unroll
        for (int j = 0; j < 8; j += 4) {
            const int n = nBase + tx * 8 + j;
            if (n < NOUT) {
                float4 v = {acc[i][j], acc[i][j + 1], acc[i][j + 2], acc[i][j + 3]};
                *(float4*)(proj + (size_t)m * NOUT + n) = v;
            }
        }
    }
}

// -------------------------------------------------------------------------
// Kernel 2: per-pair tanh + 300x4 matvec + softmax. One wave per pair.
// -------------------------------------------------------------------------
__global__ __launch_bounds__(256) void bert_pair_mlp_kernel(
    const float* __restrict__ proj, const float* __restrict__ b1,
    const float* __restrict__ w2, const float* __restrict__ b2,
    const int* __restrict__ pair_idx, float* __restrict__ out)
{
    const int wid  = (int)((blockIdx.x * blockDim.x + threadIdx.x) >> 6); // pair id
    const int lane = threadIdx.x & 63;
    if (wid >= Bb * Pp) return;

    const int b  = wid >> 10;              // / Pp
    const int i0 = pair_idx[wid * 2 + 0];
    const int i1 = pair_idx[wid * 2 + 1];

    const float* r0 = (i0 >= 0) ? proj + ((size_t)(b * Ww + i0) * NOUT)       : nullptr;
    const float* r1 = (i1 >= 0) ? proj + ((size_t)(b * Ww + i1) * NOUT + NH)  : nullptr;

    float acc0 = 0.f, acc1 = 0.f, acc2 = 0.f, acc3 = 0.f;
    for (int j = lane; j < NH; j += 64) {
        float v = b1[j];
        if (r0) v += r0[j];
        if (r1) v += r1[j];
        const float x = tanhf(v);
        const float4 wv = *(const float4*)(w2 + (size_t)j * 4);
        acc0 = fmaf(x, wv.x, acc0);
        acc1 = fmaf(x, wv.y, acc1);
        acc2 = fmaf(x, wv.z, acc2);
        acc3 = fmaf(x, wv.w, acc3);
    }
#pragma unroll
    for (int off = 32; off >= 1; off >>= 1) {
        acc0 += __shfl_xor(acc0, off, 64);
        acc1 += __shfl_xor(acc1, off, 64);
        acc2 += __shfl_xor(acc2, off, 64);
        acc3 += __shfl_xor(acc3, off, 64);
    }
    if (lane == 0) {
        float l0 = acc0 + b2[0];
        float l1 = acc1 + b2[1];
        float l2 = acc2 + b2[2];
        float l3 = acc3 + b2[3];
        float mx = fmaxf(fmaxf(l0, l1), fmaxf(l2, l3));
        float e0 = expf(l0 - mx), e1 = expf(l1 - mx);
        float e2 = expf(l2 - mx), e3 = expf(l3 - mx);
        float inv = 1.0f / (e0 + e1 + e2 + e3);
        float4 o = {e0 * inv, e1 * inv, e2 * inv, e3 * inv};
        *(float4*)(out + (size_t)wid * 4) = o;
    }
}

// -------------------------------------------------------------------------
extern "C" void kernel_launch(void* const* d_in, const int* in_sizes, int n_in,
                              void* d_out, int out_size, void* d_ws, size_t ws_size,
                              hipStream_t stream)
{
    const float* h          = (const float*)d_in[0];
    const float* w1         = (const float*)d_in[1];
    const float* b1         = (const float*)d_in[2];
    const float* w2         = (const float*)d_in[3];
    const float* b2         = (const float*)d_in[4];
    const int*   word_start = (const int*)d_in[5];
    const int*   word_len   = (const int*)d_in[6];
    const int*   pair_idx   = (const int*)d_in[7];
    float*       out        = (float*)d_out;
    float*       proj       = (float*)d_ws;   // [Mm][NOUT] fp32 = 19.66 MB

    dim3 g1(5, 128);   // ceil(600/128)=5 N-tiles, 8192/64=128 M-tiles
    bert_pool_gemm_kernel<<<g1, dim3(256), 0, stream>>>(h, w1, word_start, word_len, proj);

    // 32768 pairs, one 64-lane wave each, 4 waves per 256-thread block
    bert_pair_mlp_kernel<<<dim3(8192), dim3(256), 0, stream>>>(proj, b1, w2, b2, pair_idx, out);
}

// Round 2
// 80.081 us; speedup vs baseline: 2.8233x; 2.8233x over previous
//
#include <hip/hip_runtime.h>
#include <cstddef>
#include <cstdint>

// Problem constants
#define Bb   32
#define Ss   512
#define Dd   768
#define Ww   256
#define Pp   1024
#define NH   300          // hidden
#define NPAD 640          // padded N (600 real cols + 40 zero)
#define Mm   (Bb * Ww)    // 8192 words

typedef __attribute__((ext_vector_type(8))) short bf16x8;
typedef __attribute__((ext_vector_type(4))) float f32x4;

#define GPTR(p) ((const __attribute__((address_space(1))) void*)(p))
#define LPTR(p) ((__attribute__((address_space(3))) void*)(p))

__device__ __forceinline__ unsigned short f2bf(float x) {
    unsigned u = __builtin_bit_cast(unsigned, x);
    u += 0x7fffu + ((u >> 16) & 1u);          // RNE
    return (unsigned short)(u >> 16);
}

// -------------------------------------------------------------------------
// Kernel 1: mean-pool subwords -> word embeddings, f32 -> bf16.
// One block per word (192 threads = 192 float4 = 768 floats).
// -------------------------------------------------------------------------
__global__ __launch_bounds__(192) void pool_kernel(
    const float* __restrict__ h, const int* __restrict__ word_start,
    const int* __restrict__ word_len, unsigned short* __restrict__ emb)
{
    const int m = blockIdx.x;          // word id = b*W + w
    const int t = threadIdx.x;         // 0..191
    const int b  = m >> 8;
    const int s0 = word_start[m];
    const int len = word_len[m];

    const float* p = h + (size_t)b * (Ss * Dd) + (size_t)s0 * Dd + t * 4;
    float4 v = *(const float4*)p;
    if (len == 2) {
        float4 v2 = *(const float4*)(p + Dd);
        v.x = (v.x + v2.x) * 0.5f;
        v.y = (v.y + v2.y) * 0.5f;
        v.z = (v.z + v2.z) * 0.5f;
        v.w = (v.w + v2.w) * 0.5f;
    }
    ushort4 o = make_ushort4(f2bf(v.x), f2bf(v.y), f2bf(v.z), f2bf(v.w));
    *(ushort4*)(emb + (size_t)m * Dd + t * 4) = o;
}

// -------------------------------------------------------------------------
// Kernel 2: repack w1 [1536][300] f32 -> BmatT [640][768] bf16 (N-transposed)
//   BmatT[n][k] = n<300 ? w1[k][n] : (n<600 ? w1[768+k][n-300] : 0)
// -------------------------------------------------------------------------
__global__ __launch_bounds__(256) void repack_kernel(
    const float* __restrict__ w1, unsigned short* __restrict__ bmatT)
{
    const int n = blockIdx.y;                      // 0..639
    const int k = blockIdx.x * 256 + threadIdx.x;  // 0..767
    float v = 0.0f;
    if (n < NH)            v = w1[(size_t)k * NH + n];
    else if (n < 2 * NH)   v = w1[(size_t)(Dd + k) * NH + (n - NH)];
    bmatT[(size_t)n * Dd + k] = f2bf(v);
}

// -------------------------------------------------------------------------
// Kernel 3: MFMA bf16 GEMM: proj[8192][640] = emb[8192][768] @ Bmat[768][640]
// Tile 64x128, BK=32, 256 threads = 4 waves (2x2), each wave 32x64 (2x4 frags).
// LDS layout [kblock][row][8] -> conflict-free ds_read_b128, linear staging.
// -------------------------------------------------------------------------
__global__ __launch_bounds__(256) void gemm_kernel(
    const unsigned short* __restrict__ emb, const unsigned short* __restrict__ bmatT,
    float* __restrict__ proj)
{
    __shared__ bf16x8 Al[4][64];    // [kb][row]  : 4 KB
    __shared__ bf16x8 Bl[4][128];   // [kb][ncol] : 8 KB

    const int t     = threadIdx.x;
    const int mBase = blockIdx.y * 64;
    const int nBase = blockIdx.x * 128;

    // staging roles (LDS dest byte offset == t*16, linear in t)
    const unsigned short* srcA = emb   + (size_t)(mBase + (t & 63))  * Dd + ((t >> 6) << 3);
    const unsigned short* srcB = bmatT + (size_t)(nBase + (t & 127)) * Dd + ((t >> 7) << 3);
    char* ldsA  = (char*)Al + t * 16;
    char* ldsB0 = (char*)Bl + t * 16;
    char* ldsB1 = ldsB0 + 4096;     // chunk t+256 -> kb+2 -> +16 elems on src

    // compute roles
    const int lane = t & 63;
    const int w    = t >> 6;
    const int wr   = w >> 1;        // 0..1 (row half)
    const int wc   = w & 1;         // 0..1 (col half)
    const int fr   = lane & 15;
    const int kb   = lane >> 4;

    f32x4 acc[2][4];
#pragma unroll
    for (int i = 0; i < 2; ++i)
#pragma unroll
        for (int j = 0; j < 4; ++j)
#pragma unroll
            for (int r = 0; r < 4; ++r) acc[i][j][r] = 0.0f;

    const int arow = wr * 32 + fr;
    const int brow = wc * 64 + fr;

    for (int k0 = 0; k0 < Dd; k0 += 32) {
        __syncthreads();   // previous iteration done reading LDS
        __builtin_amdgcn_global_load_lds(GPTR(srcA),      LPTR(ldsA),  16, 0, 0);
        __builtin_amdgcn_global_load_lds(GPTR(srcB),      LPTR(ldsB0), 16, 0, 0);
        __builtin_amdgcn_global_load_lds(GPTR(srcB + 16), LPTR(ldsB1), 16, 0, 0);
        srcA += 32; srcB += 32;
        __syncthreads();   // implicit vmcnt(0) drain + barrier

        bf16x8 a0 = Al[kb][arow];
        bf16x8 a1 = Al[kb][arow + 16];
        bf16x8 b0 = Bl[kb][brow];
        bf16x8 b1 = Bl[kb][brow + 16];
        bf16x8 b2 = Bl[kb][brow + 32];
        bf16x8 b3 = Bl[kb][brow + 48];
        acc[0][0] = __builtin_amdgcn_mfma_f32_16x16x32_bf16(a0, b0, acc[0][0], 0, 0, 0);
        acc[0][1] = __builtin_amdgcn_mfma_f32_16x16x32_bf16(a0, b1, acc[0][1], 0, 0, 0);
        acc[0][2] = __builtin_amdgcn_mfma_f32_16x16x32_bf16(a0, b2, acc[0][2], 0, 0, 0);
        acc[0][3] = __builtin_amdgcn_mfma_f32_16x16x32_bf16(a0, b3, acc[0][3], 0, 0, 0);
        acc[1][0] = __builtin_amdgcn_mfma_f32_16x16x32_bf16(a1, b0, acc[1][0], 0, 0, 0);
        acc[1][1] = __builtin_amdgcn_mfma_f32_16x16x32_bf16(a1, b1, acc[1][1], 0, 0, 0);
        acc[1][2] = __builtin_amdgcn_mfma_f32_16x16x32_bf16(a1, b2, acc[1][2], 0, 0, 0);
        acc[1][3] = __builtin_amdgcn_mfma_f32_16x16x32_bf16(a1, b3, acc[1][3], 0, 0, 0);
    }

    // C/D layout: col = lane&15, row = (lane>>4)*4 + r   [verified m89/m91]
    const int r0 = mBase + wr * 32 + kb * 4;
    const int c0 = nBase + wc * 64 + fr;
#pragma unroll
    for (int mi = 0; mi < 2; ++mi)
#pragma unroll
        for (int ni = 0; ni < 4; ++ni)
#pragma unroll
            for (int r = 0; r < 4; ++r)
                proj[(size_t)(r0 + mi * 16 + r) * NPAD + c0 + ni * 16] = acc[mi][ni][r];
}

// -------------------------------------------------------------------------
// Kernel 4: per-pair tanh + 300x4 matvec + softmax. One wave per pair.
// -------------------------------------------------------------------------
__global__ __launch_bounds__(256) void bert_pair_mlp_kernel(
    const float* __restrict__ proj, const float* __restrict__ b1,
    const float* __restrict__ w2, const float* __restrict__ b2,
    const int* __restrict__ pair_idx, float* __restrict__ out)
{
    const int wid  = (int)((blockIdx.x * blockDim.x + threadIdx.x) >> 6);
    const int lane = threadIdx.x & 63;
    if (wid >= Bb * Pp) return;

    const int b  = wid >> 10;
    const int i0 = pair_idx[wid * 2 + 0];
    const int i1 = pair_idx[wid * 2 + 1];

    const float* r0 = (i0 >= 0) ? proj + ((size_t)(b * Ww + i0) * NPAD)      : nullptr;
    const float* r1 = (i1 >= 0) ? proj + ((size_t)(b * Ww + i1) * NPAD + NH) : nullptr;

    float acc0 = 0.f, acc1 = 0.f, acc2 = 0.f, acc3 = 0.f;
    for (int j = lane; j < NH; j += 64) {
        float v = b1[j];
        if (r0) v += r0[j];
        if (r1) v += r1[j];
        const float x = tanhf(v);
        const float4 wv = *(const float4*)(w2 + (size_t)j * 4);
        acc0 = fmaf(x, wv.x, acc0);
        acc1 = fmaf(x, wv.y, acc1);
        acc2 = fmaf(x, wv.z, acc2);
        acc3 = fmaf(x, wv.w, acc3);
    }
#pragma unroll
    for (int off = 32; off >= 1; off >>= 1) {
        acc0 += __shfl_xor(acc0, off, 64);
        acc1 += __shfl_xor(acc1, off, 64);
        acc2 += __shfl_xor(acc2, off, 64);
        acc3 += __shfl_xor(acc3, off, 64);
    }
    if (lane == 0) {
        float l0 = acc0 + b2[0];
        float l1 = acc1 + b2[1];
        float l2 = acc2 + b2[2];
        float l3 = acc3 + b2[3];
        float mx = fmaxf(fmaxf(l0, l1), fmaxf(l2, l3));
        float e0 = expf(l0 - mx), e1 = expf(l1 - mx);
        float e2 = expf(l2 - mx), e3 = expf(l3 - mx);
        float inv = 1.0f / (e0 + e1 + e2 + e3);
        float4 o = {e0 * inv, e1 * inv, e2 * inv, e3 * inv};
        *(float4*)(out + (size_t)wid * 4) = o;
    }
}

// -------------------------------------------------------------------------
extern "C" void kernel_launch(void* const* d_in, const int* in_sizes, int n_in,
                              void* d_out, int out_size, void* d_ws, size_t ws_size,
                              hipStream_t stream)
{
    const float* h          = (const float*)d_in[0];
    const float* w1         = (const float*)d_in[1];
    const float* b1         = (const float*)d_in[2];
    const float* w2         = (const float*)d_in[3];
    const float* b2         = (const float*)d_in[4];
    const int*   word_start = (const int*)d_in[5];
    const int*   word_len   = (const int*)d_in[6];
    const int*   pair_idx   = (const int*)d_in[7];
    float*       out        = (float*)d_out;

    // workspace layout
    float*          proj  = (float*)d_ws;                                   // 8192*640*4  = 20971520 B
    unsigned short* emb   = (unsigned short*)((char*)d_ws + 20971520);      // 8192*768*2  = 12582912 B
    unsigned short* bmatT = (unsigned short*)((char*)d_ws + 20971520 + 12582912); // 640*768*2 = 983040 B

    pool_kernel  <<<dim3(Mm),      dim3(192), 0, stream>>>(h, word_start, word_len, emb);
    repack_kernel<<<dim3(3, NPAD), dim3(256), 0, stream>>>(w1, bmatT);
    gemm_kernel  <<<dim3(5, 128),  dim3(256), 0, stream>>>(emb, bmatT, proj);
    bert_pair_mlp_kernel<<<dim3(8192), dim3(256), 0, stream>>>(proj, b1, w2, b2, pair_idx, out);
}

// Round 3
// 69.723 us; speedup vs baseline: 3.2427x; 1.1486x over previous
//
#include <hip/hip_runtime.h>
#include <cstddef>
#include <cstdint>

// Problem constants
#define Bb   32
#define Ss   512
#define Dd   768
#define Ww   256
#define Pp   1024
#define NH   300          // hidden
#define NPAD 640          // padded N (600 real + 40 zero)
#define Mm   (Bb * Ww)    // 8192 words

typedef __attribute__((ext_vector_type(8))) short bf16x8;
typedef __attribute__((ext_vector_type(4))) float f32x4;

#define GPTR(p) ((const __attribute__((address_space(1))) void*)(p))
#define LPTR(p) ((__attribute__((address_space(3))) void*)(p))

__device__ __forceinline__ unsigned short f2bf(float x) {
    unsigned u = __builtin_bit_cast(unsigned, x);
    u += 0x7fffu + ((u >> 16) & 1u);          // RNE
    return (unsigned short)(u >> 16);
}
__device__ __forceinline__ float bf2f(unsigned short u) {
    return __builtin_bit_cast(float, (unsigned)u << 16);
}

// -------------------------------------------------------------------------
// Kernel 1 (prep): blocks [0, 8192): mean-pool h -> emb bf16 (one word/block)
//                  blocks [8192, 8192+2560): repack w1 -> BmatT bf16
//   BmatT[n][k] = n<300 ? w1[k][n] : (n<600 ? w1[768+k][n-300] : 0)
// -------------------------------------------------------------------------
__global__ __launch_bounds__(192) void prep_kernel(
    const float* __restrict__ h, const float* __restrict__ w1,
    const int* __restrict__ word_start, const int* __restrict__ word_len,
    unsigned short* __restrict__ emb, unsigned short* __restrict__ bmatT)
{
    const int bid = blockIdx.x;
    const int t   = threadIdx.x;      // 0..191
    if (bid < Mm) {
        const int m   = bid;
        const int b   = m >> 8;
        const int s0  = word_start[m];
        const int len = word_len[m];
        const float* p = h + (size_t)b * (Ss * Dd) + (size_t)s0 * Dd + t * 4;
        float4 v = *(const float4*)p;
        if (len == 2) {
            float4 v2 = *(const float4*)(p + Dd);
            v.x = (v.x + v2.x) * 0.5f;
            v.y = (v.y + v2.y) * 0.5f;
            v.z = (v.z + v2.z) * 0.5f;
            v.w = (v.w + v2.w) * 0.5f;
        }
        ushort4 o = make_ushort4(f2bf(v.x), f2bf(v.y), f2bf(v.z), f2bf(v.w));
        *(ushort4*)(emb + (size_t)m * Dd + t * 4) = o;
    } else {
        const int rb = bid - Mm;
        const int n  = rb >> 2;                 // 0..639
        const int k  = ((rb & 3) * 192) + t;    // 0..767
        float v = 0.0f;
        if (n < NH)            v = w1[(size_t)k * NH + n];
        else if (n < 2 * NH)   v = w1[(size_t)(Dd + k) * NH + (n - NH)];
        bmatT[(size_t)n * Dd + k] = f2bf(v);
    }
}

// -------------------------------------------------------------------------
// Kernel 2: MFMA bf16 GEMM: proj[8192][640] = emb[8192][768] @ Bmat[768][640]
// Tile 128x128, BK=32, 256 threads = 4 waves (2x2), each wave 64x64 (4x4).
// LDS [kb][row][bf16x8]; global_load_lds width 16, linear dest (rule #21).
// XCD-chunked bijective swizzle over the 320-block 1D grid (320 = 8*40).
// proj written as bf16.
// -------------------------------------------------------------------------
__global__ __launch_bounds__(256) void gemm_kernel(
    const unsigned short* __restrict__ emb, const unsigned short* __restrict__ bmatT,
    unsigned short* __restrict__ proj)
{
    __shared__ bf16x8 Al[4][128];   // 8 KB
    __shared__ bf16x8 Bl[4][128];   // 8 KB

    // bijective XCD swizzle: 320 blocks, 8 XCDs, 40 per chunk
    const int swz   = (blockIdx.x & 7) * 40 + (blockIdx.x >> 3);
    const int mBase = (swz / 5) * 128;
    const int nBase = (swz % 5) * 128;

    const int t = threadIdx.x;

    // staging roles: chunk c = t and c = t+256; kb = c>>7, row = c&127
    const int srow = t & 127;
    const int skb  = t >> 7;
    const unsigned short* srcA = emb   + (size_t)(mBase + srow) * Dd + (skb << 3);
    const unsigned short* srcB = bmatT + (size_t)(nBase + srow) * Dd + (skb << 3);
    char* ldsA = (char*)Al + t * 16;
    char* ldsB = (char*)Bl + t * 16;

    // compute roles
    const int lane = t & 63;
    const int w    = t >> 6;
    const int wr   = w >> 1;
    const int wc   = w & 1;
    const int fr   = lane & 15;
    const int kb   = lane >> 4;

    f32x4 acc[4][4];
#pragma unroll
    for (int i = 0; i < 4; ++i)
#pragma unroll
        for (int j = 0; j < 4; ++j)
#pragma unroll
            for (int r = 0; r < 4; ++r) acc[i][j][r] = 0.0f;

    for (int k0 = 0; k0 < Dd; k0 += 32) {
        __syncthreads();   // previous iteration done reading LDS
        __builtin_amdgcn_global_load_lds(GPTR(srcA),      LPTR(ldsA),        16, 0, 0);
        __builtin_amdgcn_global_load_lds(GPTR(srcA + 16), LPTR(ldsA + 4096), 16, 0, 0);
        __builtin_amdgcn_global_load_lds(GPTR(srcB),      LPTR(ldsB),        16, 0, 0);
        __builtin_amdgcn_global_load_lds(GPTR(srcB + 16), LPTR(ldsB + 4096), 16, 0, 0);
        srcA += 32; srcB += 32;
        __syncthreads();   // vmcnt(0) drain + barrier

        bf16x8 a[4], b[4];
#pragma unroll
        for (int mi = 0; mi < 4; ++mi) a[mi] = Al[kb][wr * 64 + mi * 16 + fr];
#pragma unroll
        for (int ni = 0; ni < 4; ++ni) b[ni] = Bl[kb][wc * 64 + ni * 16 + fr];
#pragma unroll
        for (int mi = 0; mi < 4; ++mi)
#pragma unroll
            for (int ni = 0; ni < 4; ++ni)
                acc[mi][ni] = __builtin_amdgcn_mfma_f32_16x16x32_bf16(a[mi], b[ni], acc[mi][ni], 0, 0, 0);
    }

    // C/D layout: col = lane&15, row = (lane>>4)*4 + r   [verified m89/m91]
    const int r0 = mBase + wr * 64 + kb * 4;
    const int c0 = nBase + wc * 64 + fr;
#pragma unroll
    for (int mi = 0; mi < 4; ++mi)
#pragma unroll
        for (int ni = 0; ni < 4; ++ni)
#pragma unroll
            for (int r = 0; r < 4; ++r)
                proj[(size_t)(r0 + mi * 16 + r) * NPAD + c0 + ni * 16] = f2bf(acc[mi][ni][r]);
}

// -------------------------------------------------------------------------
// Kernel 3: per-pair tanh + 300x4 matvec + softmax. One wave per pair.
// proj is bf16 [8192][640]; slot0 cols 0..299, slot1 cols 300..599.
// -------------------------------------------------------------------------
__global__ __launch_bounds__(256) void bert_pair_mlp_kernel(
    const unsigned short* __restrict__ proj, const float* __restrict__ b1,
    const float* __restrict__ w2, const float* __restrict__ b2,
    const int* __restrict__ pair_idx, float* __restrict__ out)
{
    const int wid  = (int)((blockIdx.x * blockDim.x + threadIdx.x) >> 6);
    const int lane = threadIdx.x & 63;
    if (wid >= Bb * Pp) return;

    const int b  = wid >> 10;
    const int i0 = pair_idx[wid * 2 + 0];
    const int i1 = pair_idx[wid * 2 + 1];

    const unsigned short* r0 = (i0 >= 0) ? proj + ((size_t)(b * Ww + i0) * NPAD)      : nullptr;
    const unsigned short* r1 = (i1 >= 0) ? proj + ((size_t)(b * Ww + i1) * NPAD + NH) : nullptr;

    float acc0 = 0.f, acc1 = 0.f, acc2 = 0.f, acc3 = 0.f;
    for (int j = lane; j < NH; j += 64) {
        float v = b1[j];
        if (r0) v += bf2f(r0[j]);
        if (r1) v += bf2f(r1[j]);
        const float x = tanhf(v);
        const float4 wv = *(const float4*)(w2 + (size_t)j * 4);
        acc0 = fmaf(x, wv.x, acc0);
        acc1 = fmaf(x, wv.y, acc1);
        acc2 = fmaf(x, wv.z, acc2);
        acc3 = fmaf(x, wv.w, acc3);
    }
#pragma unroll
    for (int off = 32; off >= 1; off >>= 1) {
        acc0 += __shfl_xor(acc0, off, 64);
        acc1 += __shfl_xor(acc1, off, 64);
        acc2 += __shfl_xor(acc2, off, 64);
        acc3 += __shfl_xor(acc3, off, 64);
    }
    if (lane == 0) {
        float l0 = acc0 + b2[0];
        float l1 = acc1 + b2[1];
        float l2 = acc2 + b2[2];
        float l3 = acc3 + b2[3];
        float mx = fmaxf(fmaxf(l0, l1), fmaxf(l2, l3));
        float e0 = expf(l0 - mx), e1 = expf(l1 - mx);
        float e2 = expf(l2 - mx), e3 = expf(l3 - mx);
        float inv = 1.0f / (e0 + e1 + e2 + e3);
        float4 o = {e0 * inv, e1 * inv, e2 * inv, e3 * inv};
        *(float4*)(out + (size_t)wid * 4) = o;
    }
}

// -------------------------------------------------------------------------
extern "C" void kernel_launch(void* const* d_in, const int* in_sizes, int n_in,
                              void* d_out, int out_size, void* d_ws, size_t ws_size,
                              hipStream_t stream)
{
    const float* h          = (const float*)d_in[0];
    const float* w1         = (const float*)d_in[1];
    const float* b1         = (const float*)d_in[2];
    const float* w2         = (const float*)d_in[3];
    const float* b2         = (const float*)d_in[4];
    const int*   word_start = (const int*)d_in[5];
    const int*   word_len   = (const int*)d_in[6];
    const int*   pair_idx   = (const int*)d_in[7];
    float*       out        = (float*)d_out;

    // workspace layout (all bf16)
    unsigned short* proj  = (unsigned short*)d_ws;                        // 8192*640*2 = 10485760 B
    unsigned short* emb   = (unsigned short*)((char*)d_ws + 10485760);    // 8192*768*2 = 12582912 B
    unsigned short* bmatT = (unsigned short*)((char*)d_ws + 10485760 + 12582912); // 640*768*2

    prep_kernel<<<dim3(Mm + 4 * NPAD), dim3(192), 0, stream>>>(h, w1, word_start, word_len, emb, bmatT);
    gemm_kernel<<<dim3(320), dim3(256), 0, stream>>>(emb, bmatT, proj);
    bert_pair_mlp_kernel<<<dim3(8192), dim3(256), 0, stream>>>(proj, b1, w2, b2, pair_idx, out);
}